// Round 1
// 317.567 us; speedup vs baseline: 1.0463x; 1.0463x over previous
//
#include <hip/hip_runtime.h>
#include <hip/hip_bf16.h>
#include <cstdint>
#include <math.h>

typedef __bf16 bf16;
typedef __bf16 bf16x8 __attribute__((ext_vector_type(8)));
typedef __bf16 bf16x4 __attribute__((ext_vector_type(4)));
typedef float  f32x4 __attribute__((ext_vector_type(4)));

#define LOG2E 1.4426950408889634f

#if __has_builtin(__builtin_amdgcn_exp2f)
#define EXP2(x) __builtin_amdgcn_exp2f(x)
#else
#define EXP2(x) exp2f(x)
#endif

#define AS1 __attribute__((address_space(1)))
#define AS3 __attribute__((address_space(3)))

__device__ __forceinline__ void gload_lds16(const bf16* g, bf16* l) {
    // async global->LDS, 16B/lane; LDS dest is wave-uniform base + lane*16
    __builtin_amdgcn_global_load_lds((AS1 void*)g, (AS3 void*)l, 16, 0, 0);
}

// ---------------- fp32 -> bf16 cast (4 elems/thread) ----------------
__global__ __launch_bounds__(256)
void cast_f32_bf16(const float* __restrict__ in, bf16* __restrict__ out, int n4) {
    int i = blockIdx.x * 256 + threadIdx.x;
    if (i < n4) {
        float4 v = ((const float4*)in)[i];
        bf16 o[4] = {(bf16)v.x, (bf16)v.y, (bf16)v.z, (bf16)v.w};
        *(uint64_t*)&((bf16*)out)[i * 4] = *(uint64_t*)o;
    }
}

// ---------------- Bayesian weight materialization (fp32 in, bf16 out) ----------------
__global__ __launch_bounds__(256)
void bayes_w_kernel(const float* __restrict__ mu, const float* __restrict__ rho,
                    const float* __restrict__ eps, bf16* __restrict__ out, int n) {
    int i = blockIdx.x * 256 + threadIdx.x;
    if (i < n) {
        float r = rho[i];
        float sp = (r > 15.f) ? r : log1pf(expf(r));
        out[i] = (bf16)(mu[i] + sp * eps[i]);
    }
}

__global__ __launch_bounds__(256)
void bayes_b_kernel(const float* __restrict__ mu, const float* __restrict__ rho,
                    const float* __restrict__ eps, float* __restrict__ out, int n) {
    int i = blockIdx.x * 256 + threadIdx.x;
    if (i < n) {
        float r = rho[i];
        float sp = (r > 15.f) ? r : log1pf(expf(r));
        out[i] = mu[i] + sp * eps[i];
    }
}

// ---------------- GEMM: C[M,N] = A[M,K] @ W[N,K]^T (*scale per col-range, +bias) ----------------
template <typename OutT>
__global__ __launch_bounds__(256)
void gemm_bt(const bf16* __restrict__ A, const bf16* __restrict__ W,
             OutT* __restrict__ C, const float* __restrict__ bias,
             int M, int N, int K, float q_scale, int q_cols) {
    __shared__ bf16 lA[128 * 32];
    __shared__ bf16 lB[128 * 32];

    const int lane = threadIdx.x & 63;
    const int wv   = threadIdx.x >> 6;
    const int wr   = wv >> 1, wc = wv & 1;

    // XCD-aware bijective swizzle: consecutive swizzled ids share the A-panel and
    // land on the same XCD's L2 (both launches have nwg % 8 == 0).
    const int nwg = gridDim.x * gridDim.y;
    int bidl = blockIdx.y * gridDim.x + blockIdx.x;
    if ((nwg & 7) == 0) bidl = (bidl & 7) * (nwg >> 3) + (bidl >> 3);
    const int m0 = (bidl / gridDim.x) * 128, n0 = (bidl % gridDim.x) * 128;

    const int col = lane & 15, quad = lane >> 4;
    const float scale = (n0 < q_cols) ? q_scale : 1.0f;

    const int srow  = wv * 16 + (lane >> 2);
    const int skcol = (lane & 3) * 8;

    f32x4 acc[4][4] = {};

    for (int k0 = 0; k0 < K; k0 += 32) {
#pragma unroll
        for (int r = 0; r < 2; ++r) {
            gload_lds16(A + (size_t)(m0 + r * 64 + srow) * K + k0 + skcol,
                        &lA[(r * 64 + wv * 16) * 32]);
            gload_lds16(W + (size_t)(n0 + r * 64 + srow) * K + k0 + skcol,
                        &lB[(r * 64 + wv * 16) * 32]);
        }
        __syncthreads();

        bf16x8 af[4], bfr[4];
#pragma unroll
        for (int t = 0; t < 4; ++t) {
            af[t]  = *(const bf16x8*)&lA[(wr * 64 + t * 16 + col) * 32 + quad * 8];
            bfr[t] = *(const bf16x8*)&lB[(wc * 64 + t * 16 + col) * 32 + quad * 8];
        }
#pragma unroll
        for (int i = 0; i < 4; ++i)
#pragma unroll
            for (int j = 0; j < 4; ++j)
                acc[i][j] = __builtin_amdgcn_mfma_f32_16x16x32_bf16(af[i], bfr[j], acc[i][j], 0, 0, 0);
        __syncthreads();
    }

#pragma unroll
    for (int i = 0; i < 4; ++i) {
        int row = m0 + wr * 64 + i * 16 + quad * 4;
#pragma unroll
        for (int j = 0; j < 4; ++j) {
            int cc = n0 + wc * 64 + j * 16 + col;
            float bv = bias ? bias[cc] : 0.f;
#pragma unroll
            for (int r = 0; r < 4; ++r)
                C[(size_t)(row + r) * N + cc] = (OutT)(acc[i][j][r] * scale + bv);
        }
    }
}

// ---------------- Flash attention (S^T, no-max softmax, deferred normalization) ----------------
// QKV packed [B*2048][3072]: Q | K | V, head h at cols h*64. Q pre-scaled by 0.125*log2e.
// Pipelined: K double-buffered via async DMA (issued one tile ahead, drained by the
// trailing __syncthreads vmcnt(0)); V loaded to regs one tile ahead (T14 split),
// written to LDS at the top of the next iter. sVt/sP are UNPADDED (stride 64) with an
// XOR swizzle keyed on row (elem ^= (row&7)<<3): all b128 read paths get bank group
// (ks*16 + quad*4) ^ 4*(col&7) -> conflict-free per 8-lane cycle group.
// LDS = 16 KB sK[2] + 8 KB sVt + 16 KB sP = 40960 B -> exactly 4 blocks/CU.
// Grid flattened to 1024 with XCD chunk swizzle: each XCD covers 8 (b,h) pairs
// (K/V working set 4 MB = one XCD L2).
#define SWZ(row, ec) ((row) * 64 + ((ec) ^ (((row) & 7) << 3)))

__global__ __launch_bounds__(256, 4)
void attn_kernel(const bf16* __restrict__ QKV, bf16* __restrict__ O) {
    __shared__ bf16 sK[2][64 * 64];  // 16 KB  K tiles, XOR chunk swizzle, double-buffered
    __shared__ bf16 sVt[64 * 64];    //  8 KB  V^T tile [d][kv], XOR swizzle
    __shared__ bf16 sP [128 * 64];   // 16 KB  P [q][kv], XOR swizzle; also Q staging

    const int lane = threadIdx.x & 63;
    const int wv   = threadIdx.x >> 6;
    const int col  = lane & 15, quad = lane >> 4;

    // XCD chunk swizzle on flattened grid (1024 blocks, 8 XCDs, 128 works/XCD)
    const int bid  = blockIdx.x;
    const int work = (bid & 7) * 128 + (bid >> 3);
    const int qt = work & 15, h = (work >> 4) & 15, b = work >> 8;

    const size_t rowQ0 = (size_t)b * 2048 + qt * 128;
    const bf16* Qg = QKV + rowQ0 * 3072 + h * 64;
    const bf16* Kg = QKV + (size_t)b * 2048 * 3072 + 1024 + h * 64;
    const bf16* Vg = QKV + (size_t)b * 2048 * 3072 + 2048 + h * 64;

    // K-DMA lane mapping: lane i covers row base+(i>>3); fetches global chunk (i&7)^(i>>3)
    const int rloc = lane >> 3;
    const bf16* Kdma = Kg + (size_t)(wv * 16 + rloc) * 3072 + (((lane & 7) ^ rloc) * 8);

    // ---- prologue: tile-0 K DMA + tile-0 V regs, overlapped with Q staging ----
    gload_lds16(Kdma,                    &sK[0][(wv * 16) * 64]);
    gload_lds16(Kdma + (size_t)8 * 3072, &sK[0][(wv * 16 + 8) * 64]);

    const int dc0 = wv * 8, dc1 = 32 + wv * 8;   // per-thread V d-chunks (row = lane)
    bf16x8 vr0 = *(const bf16x8*)&Vg[(size_t)lane * 3072 + dc0];
    bf16x8 vr1 = *(const bf16x8*)&Vg[(size_t)lane * 3072 + dc1];

    // stage Q tile [128][64] -> sP (swizzled)
#pragma unroll
    for (int it = 0; it < 4; ++it) {
        int c = it * 256 + threadIdx.x;
        int row = c >> 3, ec = (c & 7) * 8;
        *(bf16x8*)&sP[SWZ(row, ec)] = *(const bf16x8*)&Qg[(size_t)row * 3072 + ec];
    }
    __syncthreads();   // Q visible; also drains tile-0 K DMA + V loads
    bf16x8 qf[2][2];   // B-operand frags: B[k=quad*8+j][n=col]
#pragma unroll
    for (int mi = 0; mi < 2; ++mi)
#pragma unroll
        for (int ks = 0; ks < 2; ++ks)
            qf[mi][ks] = *(const bf16x8*)&sP[SWZ(wv * 32 + mi * 16 + col, ks * 32 + quad * 8)];
    // no barrier needed: first in-loop barrier precedes any sP overwrite

    f32x4 lsum[2] = {};
    f32x4 o[2][4] = {};
    const int cx = col & 7;

    for (int t = 0; t < 32; ++t) {
        const int p = t & 1;

        // write prefetched V regs -> sVt (prev PV readers done at trailing barrier)
#pragma unroll
        for (int j = 0; j < 8; ++j) sVt[SWZ(dc0 + j, lane)] = vr0[j];
#pragma unroll
        for (int j = 0; j < 8; ++j) sVt[SWZ(dc1 + j, lane)] = vr1[j];
        __syncthreads();   // B1: V + (already-complete) K tile visible

        // issue NEXT K tile DMA into the other buffer; latency hides under S^T+PV
        if (t < 31) {
            const bf16* kn = Kdma + (size_t)(t * 64 + 64) * 3072;
            gload_lds16(kn,                    &sK[p ^ 1][(wv * 16) * 64]);
            gload_lds16(kn + (size_t)8 * 3072, &sK[p ^ 1][(wv * 16 + 8) * 64]);
        }

        // S^T tiles: st[mi][nj] = [kv=nj*16+quad*4+r][q=wv*32+mi*16+col]
        f32x4 st[2][4];
        __builtin_amdgcn_s_setprio(1);
#pragma unroll
        for (int nj = 0; nj < 4; ++nj) {
            bf16x8 kf0 = *(const bf16x8*)&sK[p][(nj * 16 + col) * 64 + ((quad ^ cx) * 8)];
            bf16x8 kf1 = *(const bf16x8*)&sK[p][(nj * 16 + col) * 64 + (((quad ^ cx) ^ 4) * 8)];
#pragma unroll
            for (int mi = 0; mi < 2; ++mi) {
                f32x4 tacc = {0.f, 0.f, 0.f, 0.f};
                tacc = __builtin_amdgcn_mfma_f32_16x16x32_bf16(kf0, qf[mi][0], tacc, 0, 0, 0);
                tacc = __builtin_amdgcn_mfma_f32_16x16x32_bf16(kf1, qf[mi][1], tacc, 0, 0, 0);
                st[mi][nj] = tacc;
            }
        }
        __builtin_amdgcn_s_setprio(0);

        // p = exp2(s'), accumulate l in-lane, pack P -> sP (own wave's rows only)
#pragma unroll
        for (int mi = 0; mi < 2; ++mi) {
#pragma unroll
            for (int nj = 0; nj < 4; ++nj) {
                f32x4 pv;
#pragma unroll
                for (int r = 0; r < 4; ++r) pv[r] = EXP2(st[mi][nj][r]);
                lsum[mi] += pv;
                bf16x4 pk = {(bf16)pv[0], (bf16)pv[1], (bf16)pv[2], (bf16)pv[3]};
                *(bf16x4*)&sP[SWZ(wv * 32 + mi * 16 + col, nj * 16 + quad * 4)] = pk;
            }
        }

        // T14: issue NEXT V loads to regs before PV; latency hides under PV MFMAs
        if (t < 31) {
            const bf16* vn = Vg + (size_t)(t * 64 + 64 + lane) * 3072;
            vr0 = *(const bf16x8*)&vn[dc0];
            vr1 = *(const bf16x8*)&vn[dc1];
        }

        // O += P.V
        __builtin_amdgcn_s_setprio(1);
#pragma unroll
        for (int ks = 0; ks < 2; ++ks) {
            bf16x8 pf0 = *(const bf16x8*)&sP[SWZ(wv * 32 + col,      ks * 32 + quad * 8)];
            bf16x8 pf1 = *(const bf16x8*)&sP[SWZ(wv * 32 + 16 + col, ks * 32 + quad * 8)];
#pragma unroll
            for (int dj = 0; dj < 4; ++dj) {
                bf16x8 vf = *(const bf16x8*)&sVt[SWZ(dj * 16 + col, ks * 32 + quad * 8)];
                o[0][dj] = __builtin_amdgcn_mfma_f32_16x16x32_bf16(pf0, vf, o[0][dj], 0, 0, 0);
                o[1][dj] = __builtin_amdgcn_mfma_f32_16x16x32_bf16(pf1, vf, o[1][dj], 0, 0, 0);
            }
        }
        __builtin_amdgcn_s_setprio(0);
        __syncthreads();   // B2: drains next-tile K DMA + V loads; protects sVt overwrite
    }

    // epilogue: reduce l (in-lane 4 + 2 shfl across quads), O /= l
#pragma unroll
    for (int mi = 0; mi < 2; ++mi) {
        float l = lsum[mi][0] + lsum[mi][1] + lsum[mi][2] + lsum[mi][3];
        l += __shfl_xor(l, 16, 64);
        l += __shfl_xor(l, 32, 64);   // now lane (col,quad) holds l[q=wv*32+mi*16+col]
#pragma unroll
        for (int r = 0; r < 4; ++r) {
            float inv = 1.f / __shfl(l, quad * 4 + r, 64);  // l for q-row quad*4+r
            size_t row = rowQ0 + wv * 32 + mi * 16 + quad * 4 + r;
#pragma unroll
            for (int dj = 0; dj < 4; ++dj)
                O[row * 1024 + h * 64 + dj * 16 + col] = (bf16)(o[mi][dj][r] * inv);
        }
    }
}

// ---------------- launch ----------------
extern "C" void kernel_launch(void* const* d_in, const int* in_sizes, int n_in,
                              void* d_out, int out_size, void* d_ws, size_t ws_size,
                              hipStream_t stream) {
    const float* x      = (const float*)d_in[0];
    const float* q_w    = (const float*)d_in[1];
    const float* k_w    = (const float*)d_in[2];
    const float* v_mu   = (const float*)d_in[3];
    const float* v_rho  = (const float*)d_in[4];
    const float* v_eps  = (const float*)d_in[5];
    const float* p_mu   = (const float*)d_in[6];
    const float* p_rho  = (const float*)d_in[7];
    const float* p_eps  = (const float*)d_in[8];
    const float* pb_mu  = (const float*)d_in[9];
    const float* pb_rho = (const float*)d_in[10];
    const float* pb_eps = (const float*)d_in[11];
    float* out = (float*)d_out;

    const size_t MN = (size_t)8192 * 1024;
    const size_t MB = (size_t)1 << 20;
    char* ws = (char*)d_ws;
    bf16*  xb   = (bf16*)(ws);                 // 16 MB
    bf16*  wqkv = (bf16*)(ws + 16 * MB);       // 6 MB: [3072][1024] = Wq|Wk|Wv
    bf16*  pwb  = (bf16*)(ws + 22 * MB);       // 2 MB
    float* p_b  = (float*)(ws + 24 * MB);      // 4 KB
    bf16*  QKV  = (bf16*)(ws + 25 * MB);       // 48 MB: [8192][3072]
    bf16*  Ab   = xb;  // x dead after QKV projection

    const int Wsz = 1024 * 1024;
    cast_f32_bf16<<<(int)(MN / 4 / 256), 256, 0, stream>>>(x, xb, (int)(MN / 4));
    cast_f32_bf16<<<1024, 256, 0, stream>>>(q_w, wqkv, Wsz / 4);
    cast_f32_bf16<<<1024, 256, 0, stream>>>(k_w, wqkv + Wsz, Wsz / 4);
    bayes_w_kernel<<<4096, 256, 0, stream>>>(v_mu, v_rho, v_eps, wqkv + 2 * Wsz, Wsz);
    bayes_w_kernel<<<4096, 256, 0, stream>>>(p_mu, p_rho, p_eps, pwb, Wsz);
    bayes_b_kernel<<<4, 256, 0, stream>>>(pb_mu, pb_rho, pb_eps, p_b, 1024);

    // fused QKV projection: [8192][3072]; Q cols pre-scaled by 0.125*log2e
    gemm_bt<bf16><<<dim3(24, 64), 256, 0, stream>>>(xb, wqkv, QKV, nullptr,
                                                    8192, 3072, 1024, 0.125f * LOG2E, 1024);

    attn_kernel<<<dim3(1024), 256, 0, stream>>>(QKV, Ab);

    gemm_bt<float><<<dim3(8, 64), 256, 0, stream>>>(Ab, pwb, out, p_b,
                                                    8192, 1024, 1024, 1.0f, 1024);
}

// Round 2
// 301.352 us; speedup vs baseline: 1.1026x; 1.0538x over previous
//
#include <hip/hip_runtime.h>
#include <hip/hip_bf16.h>
#include <cstdint>
#include <math.h>

typedef __bf16 bf16;
typedef __bf16 bf16x8 __attribute__((ext_vector_type(8)));
typedef __bf16 bf16x4 __attribute__((ext_vector_type(4)));
typedef float  f32x4 __attribute__((ext_vector_type(4)));

#define LOG2E 1.4426950408889634f

#if __has_builtin(__builtin_amdgcn_exp2f)
#define EXP2(x) __builtin_amdgcn_exp2f(x)
#else
#define EXP2(x) exp2f(x)
#endif

#define AS1 __attribute__((address_space(1)))
#define AS3 __attribute__((address_space(3)))

__device__ __forceinline__ void gload_lds16(const bf16* g, bf16* l) {
    // async global->LDS, 16B/lane; LDS dest is wave-uniform base + lane*16
    __builtin_amdgcn_global_load_lds((AS1 void*)g, (AS3 void*)l, 16, 0, 0);
}

__device__ __forceinline__ float softplus_f(float r) {
    return (r > 15.f) ? r : log1pf(expf(r));
}

// ---------------- fused prep: x cast | q_w cast | k_w cast | v bayes | p bayes | pb bayes ----
// block ranges: [0,8192) x-cast, [8192,9216) q_w, [9216,10240) k_w,
// [10240,11264) v bayes, [11264,12288) p bayes, 12288 pb bayes. All 4 elems/thread.
__global__ __launch_bounds__(256)
void prep_kernel(const float* __restrict__ x, bf16* __restrict__ xb,
                 const float* __restrict__ q_w, const float* __restrict__ k_w,
                 bf16* __restrict__ wqkv,
                 const float* __restrict__ v_mu, const float* __restrict__ v_rho,
                 const float* __restrict__ v_eps,
                 const float* __restrict__ p_mu, const float* __restrict__ p_rho,
                 const float* __restrict__ p_eps, bf16* __restrict__ pwb,
                 const float* __restrict__ pb_mu, const float* __restrict__ pb_rho,
                 const float* __restrict__ pb_eps, float* __restrict__ p_b) {
    const int Wsz = 1024 * 1024;
    int blk = blockIdx.x;
    if (blk < 8192) {                       // x: 8M f32 -> bf16
        int i = blk * 256 + threadIdx.x;
        float4 v = ((const float4*)x)[i];
        bf16 o[4] = {(bf16)v.x, (bf16)v.y, (bf16)v.z, (bf16)v.w};
        *(uint64_t*)&xb[i * 4] = *(uint64_t*)o;
    } else if (blk < 10240) {               // q_w / k_w cast
        const float* src = (blk < 9216) ? q_w : k_w;
        bf16* dst = (blk < 9216) ? wqkv : wqkv + Wsz;
        int i = ((blk - 8192) & 1023) * 256 + threadIdx.x;
        float4 v = ((const float4*)src)[i];
        bf16 o[4] = {(bf16)v.x, (bf16)v.y, (bf16)v.z, (bf16)v.w};
        *(uint64_t*)&dst[i * 4] = *(uint64_t*)o;
    } else if (blk < 12288) {               // bayes weights
        const bool isv = blk < 11264;
        const float* mu  = isv ? v_mu  : p_mu;
        const float* rho = isv ? v_rho : p_rho;
        const float* eps = isv ? v_eps : p_eps;
        bf16* dst = isv ? wqkv + 2 * Wsz : pwb;
        int i = ((blk - 10240) & 1023) * 256 + threadIdx.x;
        float4 m = ((const float4*)mu)[i];
        float4 r = ((const float4*)rho)[i];
        float4 e = ((const float4*)eps)[i];
        bf16 o[4] = {(bf16)(m.x + softplus_f(r.x) * e.x),
                     (bf16)(m.y + softplus_f(r.y) * e.y),
                     (bf16)(m.z + softplus_f(r.z) * e.z),
                     (bf16)(m.w + softplus_f(r.w) * e.w)};
        *(uint64_t*)&dst[i * 4] = *(uint64_t*)o;
    } else {                                 // bias: 1024 f32
        int i = threadIdx.x;
        float4 m = ((const float4*)pb_mu)[i];
        float4 r = ((const float4*)pb_rho)[i];
        float4 e = ((const float4*)pb_eps)[i];
        float4 o;
        o.x = m.x + softplus_f(r.x) * e.x;
        o.y = m.y + softplus_f(r.y) * e.y;
        o.z = m.z + softplus_f(r.z) * e.z;
        o.w = m.w + softplus_f(r.w) * e.w;
        ((float4*)p_b)[i] = o;
    }
}

// ---------------- GEMM: C[M,N] = A[M,K] @ W[N,K]^T (*scale per col-range, +bias) ----------------
template <typename OutT>
__global__ __launch_bounds__(256)
void gemm_bt(const bf16* __restrict__ A, const bf16* __restrict__ W,
             OutT* __restrict__ C, const float* __restrict__ bias,
             int M, int N, int K, float q_scale, int q_cols) {
    __shared__ bf16 lA[128 * 32];
    __shared__ bf16 lB[128 * 32];

    const int lane = threadIdx.x & 63;
    const int wv   = threadIdx.x >> 6;
    const int wr   = wv >> 1, wc = wv & 1;

    // XCD-aware bijective swizzle (both launches have nwg % 8 == 0)
    const int nwg = gridDim.x * gridDim.y;
    int bidl = blockIdx.y * gridDim.x + blockIdx.x;
    if ((nwg & 7) == 0) bidl = (bidl & 7) * (nwg >> 3) + (bidl >> 3);
    const int m0 = (bidl / gridDim.x) * 128, n0 = (bidl % gridDim.x) * 128;

    const int col = lane & 15, quad = lane >> 4;
    const float scale = (n0 < q_cols) ? q_scale : 1.0f;

    const int srow  = wv * 16 + (lane >> 2);
    const int skcol = (lane & 3) * 8;

    f32x4 acc[4][4] = {};

    for (int k0 = 0; k0 < K; k0 += 32) {
#pragma unroll
        for (int r = 0; r < 2; ++r) {
            gload_lds16(A + (size_t)(m0 + r * 64 + srow) * K + k0 + skcol,
                        &lA[(r * 64 + wv * 16) * 32]);
            gload_lds16(W + (size_t)(n0 + r * 64 + srow) * K + k0 + skcol,
                        &lB[(r * 64 + wv * 16) * 32]);
        }
        __syncthreads();

        bf16x8 af[4], bfr[4];
#pragma unroll
        for (int t = 0; t < 4; ++t) {
            af[t]  = *(const bf16x8*)&lA[(wr * 64 + t * 16 + col) * 32 + quad * 8];
            bfr[t] = *(const bf16x8*)&lB[(wc * 64 + t * 16 + col) * 32 + quad * 8];
        }
#pragma unroll
        for (int i = 0; i < 4; ++i)
#pragma unroll
            for (int j = 0; j < 4; ++j)
                acc[i][j] = __builtin_amdgcn_mfma_f32_16x16x32_bf16(af[i], bfr[j], acc[i][j], 0, 0, 0);
        __syncthreads();
    }

#pragma unroll
    for (int i = 0; i < 4; ++i) {
        int row = m0 + wr * 64 + i * 16 + quad * 4;
#pragma unroll
        for (int j = 0; j < 4; ++j) {
            int cc = n0 + wc * 64 + j * 16 + col;
            float bv = bias ? bias[cc] : 0.f;
#pragma unroll
            for (int r = 0; r < 4; ++r)
                C[(size_t)(row + r) * N + cc] = (OutT)(acc[i][j][r] * scale + bv);
        }
    }
}

// ---------------- Flash attention (S^T, no-max softmax, deferred normalization) ----------------
// QKV packed [B*2048][3072]: Q | K | V, head h at cols h*64. Q pre-scaled by 0.125*log2e.
// q-block 256/block, 64/wave (raises MFMA-per-LDS-read: same kf/vf reads feed 2x MFMAs).
// K double-buffered via async DMA issued one tile ahead; V loaded to regs one tile ahead
// (T14) and written to LDS at the top of the next iter. sVt/sP unpadded (stride 64) with
// XOR swizzle keyed on row (elem ^= (row&7)<<3): b128 read paths conflict-free.
// LDS = 16 KB sK[2] + 8 KB sVt + 32 KB sP = 57344 B -> 2 blocks/CU (8 waves).
// Grid flattened to 512 with XCD chunk swizzle: each XCD covers 8 (b,h) pairs
// (K/V working set 4 MB = one XCD L2).
#define SWZ(row, ec) ((row) * 64 + ((ec) ^ (((row) & 7) << 3)))

__global__ __launch_bounds__(256, 2)
void attn_kernel(const bf16* __restrict__ QKV, bf16* __restrict__ O) {
    __shared__ bf16 sK[2][64 * 64];  // 16 KB  K tiles, XOR chunk swizzle, double-buffered
    __shared__ bf16 sVt[64 * 64];    //  8 KB  V^T tile [d][kv], XOR swizzle
    __shared__ bf16 sP [256 * 64];   // 32 KB  P [q][kv], XOR swizzle; also Q staging

    const int lane = threadIdx.x & 63;
    const int wv   = threadIdx.x >> 6;
    const int col  = lane & 15, quad = lane >> 4;

    // XCD chunk swizzle on flattened grid (512 blocks, 8 XCDs, 64 works/XCD)
    const int bid  = blockIdx.x;
    const int work = (bid & 7) * 64 + (bid >> 3);
    const int qt = work & 7, h = (work >> 3) & 15, b = work >> 7;

    const size_t rowQ0 = (size_t)b * 2048 + qt * 256;
    const bf16* Qg = QKV + rowQ0 * 3072 + h * 64;
    const bf16* Kg = QKV + (size_t)b * 2048 * 3072 + 1024 + h * 64;
    const bf16* Vg = QKV + (size_t)b * 2048 * 3072 + 2048 + h * 64;

    // K-DMA lane mapping: lane i covers row base+(i>>3); fetches global chunk (i&7)^(i>>3)
    const int rloc = lane >> 3;
    const bf16* Kdma = Kg + (size_t)(wv * 16 + rloc) * 3072 + (((lane & 7) ^ rloc) * 8);

    // ---- prologue: tile-0 K DMA + tile-0 V regs, overlapped with Q staging ----
    gload_lds16(Kdma,                    &sK[0][(wv * 16) * 64]);
    gload_lds16(Kdma + (size_t)8 * 3072, &sK[0][(wv * 16 + 8) * 64]);

    const int dc0 = wv * 8, dc1 = 32 + wv * 8;   // per-thread V d-chunks (row = lane)
    bf16x8 vr0 = *(const bf16x8*)&Vg[(size_t)lane * 3072 + dc0];
    bf16x8 vr1 = *(const bf16x8*)&Vg[(size_t)lane * 3072 + dc1];

    // stage Q tile [256][64] -> sP (swizzled)
#pragma unroll
    for (int it = 0; it < 8; ++it) {
        int c = it * 256 + threadIdx.x;
        int row = c >> 3, ec = (c & 7) * 8;
        *(bf16x8*)&sP[SWZ(row, ec)] = *(const bf16x8*)&Qg[(size_t)row * 3072 + ec];
    }
    __syncthreads();   // Q visible; also drains tile-0 K DMA
    bf16x8 qf[4][2];   // B-operand frags: B[k=quad*8+j][n=col], q-rows wv*64+mi*16+col
#pragma unroll
    for (int mi = 0; mi < 4; ++mi)
#pragma unroll
        for (int ks = 0; ks < 2; ++ks)
            qf[mi][ks] = *(const bf16x8*)&sP[SWZ(wv * 64 + mi * 16 + col, ks * 32 + quad * 8)];
    // no barrier needed: first in-loop barrier precedes any sP overwrite

    f32x4 lsum[4] = {};
    f32x4 o[4][4] = {};
    const int cx = col & 7;

    for (int t = 0; t < 32; ++t) {
        const int p = t & 1;

        // write prefetched V regs -> sVt (prev PV readers done at trailing barrier)
#pragma unroll
        for (int j = 0; j < 8; ++j) sVt[SWZ(dc0 + j, lane)] = vr0[j];
#pragma unroll
        for (int j = 0; j < 8; ++j) sVt[SWZ(dc1 + j, lane)] = vr1[j];
        __syncthreads();   // B1: V + (already-complete) K tile visible

        // issue NEXT K tile DMA into the other buffer; latency hides under S^T+PV
        if (t < 31) {
            const bf16* kn = Kdma + (size_t)(t * 64 + 64) * 3072;
            gload_lds16(kn,                    &sK[p ^ 1][(wv * 16) * 64]);
            gload_lds16(kn + (size_t)8 * 3072, &sK[p ^ 1][(wv * 16 + 8) * 64]);
        }

        // K frags once per tile (shared across all 4 mi)
        bf16x8 kf0[4], kf1[4];
#pragma unroll
        for (int nj = 0; nj < 4; ++nj) {
            kf0[nj] = *(const bf16x8*)&sK[p][(nj * 16 + col) * 64 + ((quad ^ cx) * 8)];
            kf1[nj] = *(const bf16x8*)&sK[p][(nj * 16 + col) * 64 + (((quad ^ cx) ^ 4) * 8)];
        }

        // S^T per mi-slice: 8 MFMA -> exp2 -> lsum -> pack P -> sP (own wave's rows)
#pragma unroll
        for (int mi = 0; mi < 4; ++mi) {
            f32x4 st[4];
            __builtin_amdgcn_s_setprio(1);
#pragma unroll
            for (int nj = 0; nj < 4; ++nj) {
                f32x4 tacc = {0.f, 0.f, 0.f, 0.f};
                tacc = __builtin_amdgcn_mfma_f32_16x16x32_bf16(kf0[nj], qf[mi][0], tacc, 0, 0, 0);
                tacc = __builtin_amdgcn_mfma_f32_16x16x32_bf16(kf1[nj], qf[mi][1], tacc, 0, 0, 0);
                st[nj] = tacc;
            }
            __builtin_amdgcn_s_setprio(0);
#pragma unroll
            for (int nj = 0; nj < 4; ++nj) {
                f32x4 pv;
#pragma unroll
                for (int r = 0; r < 4; ++r) pv[r] = EXP2(st[nj][r]);
                lsum[mi] += pv;
                bf16x4 pk = {(bf16)pv[0], (bf16)pv[1], (bf16)pv[2], (bf16)pv[3]};
                *(bf16x4*)&sP[SWZ(wv * 64 + mi * 16 + col, nj * 16 + quad * 4)] = pk;
            }
        }

        // T14: issue NEXT V loads to regs before PV; latency hides under PV MFMAs
        if (t < 31) {
            const bf16* vn = Vg + (size_t)(t * 64 + 64 + lane) * 3072;
            vr0 = *(const bf16x8*)&vn[dc0];
            vr1 = *(const bf16x8*)&vn[dc1];
        }

        // O += P.V
        __builtin_amdgcn_s_setprio(1);
#pragma unroll
        for (int ks = 0; ks < 2; ++ks) {
            bf16x8 pf[4];
#pragma unroll
            for (int mi = 0; mi < 4; ++mi)
                pf[mi] = *(const bf16x8*)&sP[SWZ(wv * 64 + mi * 16 + col, ks * 32 + quad * 8)];
#pragma unroll
            for (int dj = 0; dj < 4; ++dj) {
                bf16x8 vf = *(const bf16x8*)&sVt[SWZ(dj * 16 + col, ks * 32 + quad * 8)];
#pragma unroll
                for (int mi = 0; mi < 4; ++mi)
                    o[mi][dj] = __builtin_amdgcn_mfma_f32_16x16x32_bf16(pf[mi], vf, o[mi][dj], 0, 0, 0);
            }
        }
        __builtin_amdgcn_s_setprio(0);
        __syncthreads();   // B2: drains next-tile K DMA + V loads; protects sVt overwrite
    }

    // epilogue: reduce l (in-lane 4 + 2 shfl across quads), O /= l
#pragma unroll
    for (int mi = 0; mi < 4; ++mi) {
        float l = lsum[mi][0] + lsum[mi][1] + lsum[mi][2] + lsum[mi][3];
        l += __shfl_xor(l, 16, 64);
        l += __shfl_xor(l, 32, 64);   // now lane (col,quad) holds l[q=wv*64+mi*16+col]
#pragma unroll
        for (int r = 0; r < 4; ++r) {
            float inv = 1.f / __shfl(l, quad * 4 + r, 64);  // l for q-row quad*4+r
            size_t row = rowQ0 + wv * 64 + mi * 16 + quad * 4 + r;
#pragma unroll
            for (int dj = 0; dj < 4; ++dj)
                O[row * 1024 + h * 64 + dj * 16 + col] = (bf16)(o[mi][dj][r] * inv);
        }
    }
}

// ---------------- launch ----------------
extern "C" void kernel_launch(void* const* d_in, const int* in_sizes, int n_in,
                              void* d_out, int out_size, void* d_ws, size_t ws_size,
                              hipStream_t stream) {
    const float* x      = (const float*)d_in[0];
    const float* q_w    = (const float*)d_in[1];
    const float* k_w    = (const float*)d_in[2];
    const float* v_mu   = (const float*)d_in[3];
    const float* v_rho  = (const float*)d_in[4];
    const float* v_eps  = (const float*)d_in[5];
    const float* p_mu   = (const float*)d_in[6];
    const float* p_rho  = (const float*)d_in[7];
    const float* p_eps  = (const float*)d_in[8];
    const float* pb_mu  = (const float*)d_in[9];
    const float* pb_rho = (const float*)d_in[10];
    const float* pb_eps = (const float*)d_in[11];
    float* out = (float*)d_out;

    const size_t MB = (size_t)1 << 20;
    char* ws = (char*)d_ws;
    bf16*  xb   = (bf16*)(ws);                 // 16 MB
    bf16*  wqkv = (bf16*)(ws + 16 * MB);       // 6 MB: [3072][1024] = Wq|Wk|Wv
    bf16*  pwb  = (bf16*)(ws + 22 * MB);       // 2 MB
    float* p_b  = (float*)(ws + 24 * MB);      // 4 KB
    bf16*  QKV  = (bf16*)(ws + 25 * MB);       // 48 MB: [8192][3072]
    bf16*  Ab   = xb;  // x dead after QKV projection

    prep_kernel<<<12289, 256, 0, stream>>>(x, xb, q_w, k_w, wqkv,
                                           v_mu, v_rho, v_eps,
                                           p_mu, p_rho, p_eps, pwb,
                                           pb_mu, pb_rho, pb_eps, p_b);

    // fused QKV projection: [8192][3072]; Q cols pre-scaled by 0.125*log2e
    gemm_bt<bf16><<<dim3(24, 64), 256, 0, stream>>>(xb, wqkv, QKV, nullptr,
                                                    8192, 3072, 1024, 0.125f * LOG2E, 1024);

    attn_kernel<<<dim3(512), 256, 0, stream>>>(QKV, Ab);

    gemm_bt<float><<<dim3(8, 64), 256, 0, stream>>>(Ab, pwb, out, p_b,
                                                    8192, 1024, 1024, 1.0f, 1024);
}